// Round 7
// baseline (66.444 us; speedup 1.0000x reference)
//
#include <hip/hip_runtime.h>

// out[i, 7n+o, m] = sum_{j,k} x[j, 7n+o+k-1, m] * W[i,j,k], taps clipped to o+k-1 in [0,7)
// x: (48,56,56) f32, W: (192,48,3) f32, out: (192,56,56) f32
//
// R7: measurement-decomposition probe. Identical R6 kernel, launched TWICE
// back-to-back on `stream` (serialized, idempotent -> same output, passes).
// total_R7 - total_R6 = T_kernel exactly, independent of harness-constant
// calibration. Decides whether further kernel optimization can matter.

#define CH_IN 48
#define CH_OUT 192
#define HW 56
#define SP 3136   // 56*56
#define OB 7      // rows per n-block
#define M4 14     // float4 chunks per 56-wide row
#define COLS 112  // spatial columns per channel
#define SEGS 16
#define JSEG 3    // 48/16
#define BCOL 8    // columns per block
#define IG 4      // output channels per thread
#define CG 14     // colgroups per channel (112/8)
#define WST 144   // 48*3 floats per W row

__device__ __forceinline__ void fma4(float4& a, float s, const float4& b) {
    a.x += s * b.x; a.y += s * b.y; a.z += s * b.z; a.w += s * b.w;
}
__device__ __forceinline__ void add4(float4& a, const float4& b) {
    a.x += b.x; a.y += b.y; a.z += b.z; a.w += b.w;
}

__global__ __launch_bounds__(128, 2) void conv_ig4_kernel(const float* __restrict__ x,
                                                          const float* __restrict__ W,
                                                          float* __restrict__ out) {
    __shared__ float4 red[SEGS][2][OB][BCOL + 1];   // 32.25 KB

    const int tid = threadIdx.x;
    const int c   = tid & (BCOL - 1);      // column within block [0,8)
    const int seg = tid >> 3;              // j-segment [0,16)
    const int ig4 = blockIdx.x / CG;       // i-group [0,48)
    const int cg  = blockIdx.x % CG;       // colgroup [0,14)
    const int i0  = ig4 * IG;

    const int col = cg * BCOL + c;         // [0,112)
    const int n   = col / M4;
    const int m4  = col % M4;

    const float* xcol  = x + seg * (JSEG * SP) + n * (OB * HW) + m4 * 4;
    const float* wbase = W + i0 * WST + seg * (JSEG * 3);

    float4 acc[IG][OB];
#pragma unroll
    for (int ig = 0; ig < IG; ++ig)
#pragma unroll
        for (int o = 0; o < OB; ++o) acc[ig][o] = make_float4(0.f, 0.f, 0.f, 0.f);

#pragma unroll
    for (int j = 0; j < JSEG; ++j) {
        const float* xj = xcol + j * SP;
        float4 xv[OB];
#pragma unroll
        for (int o = 0; o < OB; ++o)
            xv[o] = *reinterpret_cast<const float4*>(xj + o * HW);

#pragma unroll
        for (int ig = 0; ig < IG; ++ig) {
            const float* wp = wbase + ig * WST + j * 3;
            const float w0 = wp[0];
            const float w1 = wp[1];
            const float w2 = wp[2];
#pragma unroll
            for (int o = 0; o < OB; ++o) {
                if (o > 0)      fma4(acc[ig][o], w0, xv[o - 1]);  // k=0 tap
                fma4(acc[ig][o], w1, xv[o]);                      // k=1 tap
                if (o < OB - 1) fma4(acc[ig][o], w2, xv[o + 1]);  // k=2 tap
            }
        }
    }

    // Reduce 16 segments; two phases of 2 output channels each.
#pragma unroll
    for (int p = 0; p < 2; ++p) {
        __syncthreads();
#pragma unroll
        for (int d = 0; d < 2; ++d)
#pragma unroll
            for (int o = 0; o < OB; ++o)
                red[seg][d][o][c] = acc[2 * p + d][o];
        __syncthreads();

        if (tid < 2 * OB * BCOL) {   // 112 reducers
            const int d  = tid / (OB * BCOL);
            const int r  = tid % (OB * BCOL);
            const int o  = r / BCOL;
            const int cc = r % BCOL;
            float4 s = red[0][d][o][cc];
#pragma unroll
            for (int sg = 1; sg < SEGS; ++sg) add4(s, red[sg][d][o][cc]);

            const int col2 = cg * BCOL + cc;
            const int n2   = col2 / M4;
            const int m42  = col2 % M4;
            *reinterpret_cast<float4*>(out + (i0 + 2 * p + d) * SP + n2 * (OB * HW) + o * HW + m42 * 4) = s;
        }
    }
}

extern "C" void kernel_launch(void* const* d_in, const int* in_sizes, int n_in,
                              void* d_out, int out_size, void* d_ws, size_t ws_size,
                              hipStream_t stream) {
    const float* x = (const float*)d_in[0];
    const float* W = (const float*)d_in[1];
    float* out = (float*)d_out;

    const int grid = (CH_OUT / IG) * CG;  // 672 blocks x 128 threads
    // PROBE: two identical serialized launches; marginal cost = true kernel time.
    conv_ig4_kernel<<<grid, 128, 0, stream>>>(x, W, out);
    conv_ig4_kernel<<<grid, 128, 0, stream>>>(x, W, out);
}

// Round 8
// 60.637 us; speedup vs baseline: 1.0958x; 1.0958x over previous
//
#include <hip/hip_runtime.h>

// out[i, 7n+o, m] = sum_{j,k} x[j, 7n+o+k-1, m] * W[i,j,k], taps clipped to o+k-1 in [0,7)
// x: (48,56,56) f32, W: (192,48,3) f32, out: (192,56,56) f32
//
// R8: R6 + row-split. Block = 256 thr = 8 cols x 16 j-segs x 2 rowgroups
// (rows 0-3 / 4-6, wave-uniform). Grid = 48 igroups x 14 colgroups = 672 blocks
// -> 2688 waves (2.6/SIMD, 2x R6). IG=4 register reuse kept; x traffic 37 MB.

#define CH_IN 48
#define CH_OUT 192
#define HW 56
#define SP 3136   // 56*56
#define OB 7
#define M4 14
#define SEGS 16
#define JSEG 3    // 48/16
#define BCOL 8
#define IG 4
#define CG 14     // colgroups per channel (112/8)
#define WST 144   // 48*3 floats per W row

__device__ __forceinline__ void fma4(float4& a, float s, const float4& b) {
    a.x += s * b.x; a.y += s * b.y; a.z += s * b.z; a.w += s * b.w;
}
__device__ __forceinline__ void add4(float4& a, const float4& b) {
    a.x += b.x; a.y += b.y; a.z += b.z; a.w += b.w;
}

__global__ __launch_bounds__(256, 2) void conv_rs_kernel(const float* __restrict__ x,
                                                         const float* __restrict__ W,
                                                         float* __restrict__ out) {
    __shared__ float4 red[SEGS][2][OB][BCOL + 1];   // 32.25 KB

    const int tid = threadIdx.x;
    const int c   = tid & (BCOL - 1);        // column [0,8)
    const int seg = (tid >> 3) & (SEGS - 1); // j-segment [0,16)
    const int rg  = tid >> 7;                // rowgroup (wave-uniform): 0 -> rows 0-3, 1 -> rows 4-6
    const int ig4 = blockIdx.x / CG;
    const int cg  = blockIdx.x % CG;
    const int i0  = ig4 * IG;

    const int col = cg * BCOL + c;           // [0,112)
    const int n   = col / M4;
    const int m4  = col % M4;

    const float* xcol  = x + seg * (JSEG * SP) + n * (OB * HW) + m4 * 4;
    const float* wbase = W + i0 * WST + seg * (JSEG * 3);

    float4 acc[IG][4];
#pragma unroll
    for (int ig = 0; ig < IG; ++ig)
#pragma unroll
        for (int o = 0; o < 4; ++o) acc[ig][o] = make_float4(0.f, 0.f, 0.f, 0.f);

    if (rg == 0) {
        // rows 0..3; taps touch rows 0..4 (k=0 tap of row 0 is zero-pad, skipped)
#pragma unroll
        for (int j = 0; j < JSEG; ++j) {
            const float* xj = xcol + j * SP;
            float4 xv[5];
#pragma unroll
            for (int r = 0; r < 5; ++r)
                xv[r] = *reinterpret_cast<const float4*>(xj + r * HW);
#pragma unroll
            for (int ig = 0; ig < IG; ++ig) {
                const float* wp = wbase + ig * WST + j * 3;
                const float w0 = wp[0], w1 = wp[1], w2 = wp[2];
#pragma unroll
                for (int o = 0; o < 4; ++o) {
                    if (o > 0) fma4(acc[ig][o], w0, xv[o - 1]);
                    fma4(acc[ig][o], w1, xv[o]);
                    fma4(acc[ig][o], w2, xv[o + 1]);
                }
            }
        }
    } else {
        // rows 4..6; taps touch rows 3..6 (k=2 tap of row 6 is zero-pad, skipped)
#pragma unroll
        for (int j = 0; j < JSEG; ++j) {
            const float* xj = xcol + j * SP;
            float4 xv[4];
#pragma unroll
            for (int r = 0; r < 4; ++r)
                xv[r] = *reinterpret_cast<const float4*>(xj + (3 + r) * HW);
#pragma unroll
            for (int ig = 0; ig < IG; ++ig) {
                const float* wp = wbase + ig * WST + j * 3;
                const float w0 = wp[0], w1 = wp[1], w2 = wp[2];
#pragma unroll
                for (int o2 = 0; o2 < 3; ++o2) {   // o = 4 + o2
                    fma4(acc[ig][o2], w0, xv[o2]);         // row o-1 = 3+o2
                    fma4(acc[ig][o2], w1, xv[o2 + 1]);     // row o   = 4+o2
                    if (o2 < 2) fma4(acc[ig][o2], w2, xv[o2 + 2]); // row o+1
                }
            }
        }
    }

    // Reduce 16 segments; two phases of 2 output channels each.
#pragma unroll
    for (int p = 0; p < 2; ++p) {
        __syncthreads();
#pragma unroll
        for (int d = 0; d < 2; ++d) {
            const int ch = 2 * p + d;
            if (rg == 0) {
#pragma unroll
                for (int o = 0; o < 4; ++o) red[seg][d][o][c] = acc[ch][o];
            } else {
#pragma unroll
                for (int o2 = 0; o2 < 3; ++o2) red[seg][d][4 + o2][c] = acc[ch][o2];
            }
        }
        __syncthreads();

        if (tid < 2 * OB * BCOL) {   // 112 reducers
            const int d  = tid / (OB * BCOL);
            const int r  = tid % (OB * BCOL);
            const int o  = r / BCOL;
            const int cc = r % BCOL;
            float4 s = red[0][d][o][cc];
#pragma unroll
            for (int sg = 1; sg < SEGS; ++sg) add4(s, red[sg][d][o][cc]);

            const int col2 = cg * BCOL + cc;
            const int n2   = col2 / M4;
            const int m42  = col2 % M4;
            *reinterpret_cast<float4*>(out + (i0 + 2 * p + d) * SP + n2 * (OB * HW) + o * HW + m42 * 4) = s;
        }
    }
}

extern "C" void kernel_launch(void* const* d_in, const int* in_sizes, int n_in,
                              void* d_out, int out_size, void* d_ws, size_t ws_size,
                              hipStream_t stream) {
    const float* x = (const float*)d_in[0];
    const float* W = (const float*)d_in[1];
    float* out = (float*)d_out;

    const int grid = (CH_OUT / IG) * CG;  // 672 blocks x 256 threads
    conv_rs_kernel<<<grid, 256, 0, stream>>>(x, W, out);
}